// Round 9
// baseline (463.651 us; speedup 1.0000x reference)
//
#include <hip/hip_runtime.h>

#define TT 2048     // sequence length
#define DD 256      // head dim
#define RQB 32      // q-rows per block (2 waves x 16)
#define NT 128      // 2 waves
#define KB 32       // K-cols per LDS tile (16 KB)
#define NTILE (TT / KB)   // 64
#define NITER 30
#define CAP 28      // stored candidates per row

// LDS byte layout (staging: 2 x 16 KB double buffer at offset 0)
#define L_CIDX 32768                       // u16 [RQB][CAP] = 1792
#define L_CVAL (L_CIDX + RQB * CAP * 2)    // f32 [RQB][CAP] = 3584
#define L_CNT  (L_CVAL + RQB * CAP * 4)    // int [RQB]
#define L_SLOT (L_CNT + RQB * 4)           // u16 [2][16*CAP] = 1792
#define L_OVF  (L_SLOT + 2 * 16 * CAP * 2)
#define LDS_SZ (L_OVF + 16)                // 40080 B -> 4 blocks/CU (160 KiB/4)

typedef __attribute__((ext_vector_type(4))) float f32x4;
typedef __attribute__((ext_vector_type(8))) short short8;

__device__ inline unsigned short f2bf(float x) {     // RTN fp32 -> bf16
    unsigned u = __float_as_uint(x);
    return (unsigned short)((u + 0x7fffu + ((u >> 16) & 1u)) >> 16);
}
__device__ inline float bf2f(unsigned short h) {
    return __uint_as_float((unsigned)h << 16);
}

__device__ __forceinline__ void gload16(const void* g, void* l) {
    __builtin_amdgcn_global_load_lds(
        (const __attribute__((address_space(1))) void*)g,
        (__attribute__((address_space(3))) void*)l, 16, 0, 0);
}

// max over each 16-lane group via DPP (VALU-only, no LDS-pipe traffic)
__device__ __forceinline__ float dppmax16(float m) {
    int a = __builtin_amdgcn_update_dpp(__float_as_int(m), __float_as_int(m),
                                        0xB1, 0xF, 0xF, false);   // quad_perm [1,0,3,2]
    m = fmaxf(m, __int_as_float(a));
    a = __builtin_amdgcn_update_dpp(__float_as_int(m), __float_as_int(m),
                                    0x4E, 0xF, 0xF, false);       // quad_perm [2,3,0,1]
    m = fmaxf(m, __int_as_float(a));
    a = __builtin_amdgcn_update_dpp(__float_as_int(m), __float_as_int(m),
                                    0x141, 0xF, 0xF, false);      // row_half_mirror
    m = fmaxf(m, __int_as_float(a));
    a = __builtin_amdgcn_update_dpp(__float_as_int(m), __float_as_int(m),
                                    0x140, 0xF, 0xF, false);      // row_mirror
    m = fmaxf(m, __int_as_float(a));
    return m;
}

// ---------------- helper: K -> 0.5*K bf16 (screening operand) ----------------
__global__ __launch_bounds__(256) void split_k_kernel(const float* __restrict__ K,
        unsigned short* __restrict__ Kh, int n4) {
    int i = blockIdx.x * 256 + threadIdx.x;
    const int stride = gridDim.x * 256;
    for (; i < n4; i += stride) {
        float4 v = ((const float4*)K)[i];
        unsigned short h0 = f2bf(0.5f * v.x), h1 = f2bf(0.5f * v.y);
        unsigned short h2 = f2bf(0.5f * v.z), h3 = f2bf(0.5f * v.w);
        uint2 hv;
        hv.x = (unsigned)h0 | ((unsigned)h1 << 16);
        hv.y = (unsigned)h2 | ((unsigned)h3 << 16);
        ((uint2*)Kh)[i] = hv;
    }
}

// ---------------- main fused kernel ----------------
__launch_bounds__(NT, 2)
__global__ void entmax_screen_kernel(const float* __restrict__ Q,
                                     const unsigned short* __restrict__ Kh,
                                     const float* __restrict__ Kf,
                                     const float* __restrict__ V,
                                     float* __restrict__ Out,
                                     int nwg) {
    extern __shared__ char smem[];
    unsigned short* CIDX = (unsigned short*)(smem + L_CIDX);
    float*          CVAL = (float*)(smem + L_CVAL);
    int*            CNT  = (int*)(smem + L_CNT);
    unsigned short* SLOT = (unsigned short*)(smem + L_SLOT);
    int*            POVF = (int*)(smem + L_OVF);

    const int tid = threadIdx.x;
    const int wid = tid >> 6, lane = tid & 63;
    const int l15 = lane & 15, ag = lane >> 4;
    const int wrow0 = wid * 16;

    // XCD-bijective swizzle (nwg = B*64 = 1024, divisible by 8)
    const int lb = (blockIdx.x & 7) * (nwg >> 3) + (blockIdx.x >> 3);
    const int b  = lb >> 6;                  // 64 blocks per batch
    const int t0 = (lb & 63) * RQB;

    const char* KhB = (const char*)(Kh + (size_t)b * TT * DD);

    if (tid == 0) *POVF = 0;

    // ---- A-fragments: 16 Q rows per wave, single bf16 ----
    short8 ah[8];
    {
        const float* qr = Q + (size_t)(b * TT + t0 + wrow0 + l15) * DD;
        #pragma unroll
        for (int kk = 0; kk < 8; ++kk) {
            const int d0 = kk * 32 + ag * 8;
            float4 qa = *(const float4*)(qr + d0);
            float4 qb = *(const float4*)(qr + d0 + 4);
            float qf[8] = {qa.x, qa.y, qa.z, qa.w, qb.x, qb.y, qb.z, qb.w};
            #pragma unroll
            for (int i = 0; i < 8; ++i) ah[kk][i] = (short)f2bf(qf[i]);
        }
    }

    // ---- hoisted staging offsets: per-lane global byte offsets within a tile ----
    // linear byte ofs = wid*8192 + j*1024 + lane*16 -> col cl = ofs>>9, byte wb = ofs&511
    // global byte (within tile) = cl*512 + (wb ^ ((cl&7)<<4)); LDS dest = ofs (linear)
    int gofs[8], lofs[8];
    #pragma unroll
    for (int j = 0; j < 8; ++j) {
        const int ofs = wid * 8192 + j * 1024 + lane * 16;
        const int cl = ofs >> 9, wb = ofs & 511;
        gofs[j] = cl * 512 + (wb ^ ((cl & 7) << 4));
        lofs[j] = ofs;
    }

    // ---- hoisted swizzled ds_read base pointers (even/odd kk) ----
    const int sw = (l15 & 7) << 4;
    const int qb_ = l15 * 512 + ((ag * 16) ^ (sw & 0x30));
    const char* pE = smem + qb_ + (sw & 0x40);
    const char* pO = smem + qb_ + (64 ^ (sw & 0x40));

    // prologue: stage tile 0 into buf 0
    #pragma unroll
    for (int j = 0; j < 8; ++j) gload16(KhB + gofs[j], smem + lofs[j]);
    __syncthreads();

    const unsigned long long grpmask = 0xFFFFULL << (ag * 16);
    const unsigned long long lowmask = (lane == 0) ? 0ULL : ((~0ULL) >> (64 - lane));
    float rmax[4];
    int   base[4];
    #pragma unroll
    for (int r = 0; r < 4; ++r) { rmax[r] = -3.402823466e38f; base[r] = 0; }

    // ---------------- screening pass: 64 tiles of 32 cols ----------------
    for (int t = 0; t < NTILE; ++t) {
        const int cur = t & 1;
        if (t + 1 < NTILE) {                 // stage next tile into other buffer
            const size_t gt = (size_t)(t + 1) * 16384;
            const int lb_ = (cur ^ 1) * 16384;
            #pragma unroll
            for (int j = 0; j < 8; ++j)
                gload16(KhB + gt + gofs[j], smem + lb_ + lofs[j]);
        }
        const char* pEc = pE + cur * 16384;
        const char* pOc = pO + cur * 16384;
        f32x4 acc0, acc1;
        #pragma unroll
        for (int r = 0; r < 4; ++r) { acc0[r] = 0.0f; acc1[r] = 0.0f; }
        #pragma unroll
        for (int kk = 0; kk < 8; ++kk) {
            const char* pk = (kk & 1) ? pOc : pEc;
            const short8 b0 = *(const short8*)(pk + (kk >> 1) * 128);
            const short8 b1 = *(const short8*)(pk + 8192 + (kk >> 1) * 128);
            acc0 = __builtin_amdgcn_mfma_f32_16x16x32_bf16(ah[kk], b0, acc0, 0, 0, 0);
            acc1 = __builtin_amdgcn_mfma_f32_16x16x32_bf16(ah[kk], b1, acc1, 0, 0, 0);
        }
        // per-row-group running max (DPP) + early-out candidate append
        #pragma unroll
        for (int rg = 0; rg < 4; ++rg) {
            float m = dppmax16(fmaxf(acc0[rg], acc1[rg]));
            rmax[rg] = fmaxf(rmax[rg], m);
            const float thr = rmax[rg] - 1.6f;   // slack covers bf16 screen error
            if (m > thr) {                       // tile holds a candidate for this group
                const int row = wrow0 + ag * 4 + rg;
                {
                    const bool p = acc0[rg] > thr;
                    const unsigned long long ball = __ballot(p) & grpmask;
                    if (ball) {
                        const int rank = (int)__popcll(ball & lowmask);
                        if (p && base[rg] + rank < CAP)
                            CIDX[row * CAP + base[rg] + rank] =
                                (unsigned short)((t << 5) + l15);
                        base[rg] += (int)__popcll(ball);
                    }
                }
                {
                    const bool p = acc1[rg] > thr;
                    const unsigned long long ball = __ballot(p) & grpmask;
                    if (ball) {
                        const int rank = (int)__popcll(ball & lowmask);
                        if (p && base[rg] + rank < CAP)
                            CIDX[row * CAP + base[rg] + rank] =
                                (unsigned short)((t << 5) + 16 + l15);
                        base[rg] += (int)__popcll(ball);
                    }
                }
            }
        }
        __syncthreads();
    }

    // publish counts
    #pragma unroll
    for (int rg = 0; rg < 4; ++rg) {
        if (l15 == 0) {
            CNT[wrow0 + ag * 4 + rg] = base[rg];
            if (base[rg] > CAP) *POVF = 1;
        }
    }
    __syncthreads();

    // ---------------- exact fp32 recompute of stored candidates ----------------
    int c = 0;
    if (lane < 16) {
        const int cc = CNT[wrow0 + lane];
        c = cc > CAP ? CAP : cc;
    }
    int x = c;
    #pragma unroll
    for (int off = 1; off < 16; off <<= 1) {
        const int v = __shfl_up(x, off);
        if ((lane & 15) >= off) x += v;
    }
    const int pfx = x - c;
    const int total = __shfl(x, 15);
    if (lane < 16)
        for (int i = 0; i < c; ++i)
            SLOT[wid * (16 * CAP) + pfx + i] = (unsigned short)((lane << 8) | i);
    __syncthreads();

    {
        const float* Qb = Q + (size_t)(b * TT + t0 + wrow0) * DD;
        const float* Kb = Kf + (size_t)b * TT * DD;
        for (int bs = 0; bs < total; bs += 8) {
            float4 qv[8], kv[8];
            int rl[8], ii[8];
            #pragma unroll
            for (int u = 0; u < 8; ++u) {
                const int s = bs + u;
                const int e = (s < total) ? (int)SLOT[wid * (16 * CAP) + s] : 0;
                rl[u] = e >> 8; ii[u] = e & 255;
                const int col = (s < total) ? (int)CIDX[(wrow0 + rl[u]) * CAP + ii[u]] : 0;
                qv[u] = *(const float4*)(Qb + (size_t)rl[u] * DD + lane * 4);
                kv[u] = *(const float4*)(Kb + (size_t)col * DD + lane * 4);
            }
            float sm[8];
            #pragma unroll
            for (int u = 0; u < 8; ++u) {
                float d = qv[u].x * kv[u].x;
                d = fmaf(qv[u].y, kv[u].y, d);
                d = fmaf(qv[u].z, kv[u].z, d);
                d = fmaf(qv[u].w, kv[u].w, d);
                sm[u] = d;
            }
            #pragma unroll
            for (int off = 32; off; off >>= 1)
                #pragma unroll
                for (int u = 0; u < 8; ++u) sm[u] += __shfl_xor(sm[u], off);
            #pragma unroll
            for (int u = 0; u < 8; ++u)
                if (lane == u && bs + u < total)
                    CVAL[(wrow0 + rl[u]) * CAP + ii[u]] = 0.5f * sm[u];
        }
    }
    __syncthreads();

    // ---------------- slow path (CAP overflow; ~never) ----------------
    if (*POVF) {
        if (wid == 0) {
            float* fbz = (float*)smem;          // staging buffers are dead (8KB < 32KB)
            for (int r = 0; r < RQB; ++r) {
                if (CNT[r] <= CAP) continue;
                const float* qr = Q + (size_t)(b * TT + t0 + r) * DD;
                const float* Kb = Kf + (size_t)b * TT * DD;
                for (int cc2 = lane; cc2 < TT; cc2 += 64) {
                    const float* kr = Kb + (size_t)cc2 * DD;
                    float a = 0.0f;
                    for (int d = 0; d < DD; ++d) a = fmaf(qr[d], kr[d], a);
                    fbz[cc2] = 0.5f * a;
                }
                __threadfence_block();
                float m = -3.402823466e38f;
                for (int cc2 = lane; cc2 < TT; cc2 += 64) m = fmaxf(m, fbz[cc2]);
                #pragma unroll
                for (int off = 32; off; off >>= 1) m = fmaxf(m, __shfl_xor(m, off));
                float lo = m - 1.0f, hi = m, tau;
                for (int it = 0; it < NITER; ++it) {
                    tau = 0.5f * (lo + hi);
                    float s = 0.0f;
                    for (int cc2 = lane; cc2 < TT; cc2 += 64) {
                        const float tt2 = fmaxf(fbz[cc2] - tau, 0.0f);
                        s = fmaf(tt2, tt2, s);
                    }
                    #pragma unroll
                    for (int off = 32; off; off >>= 1) s += __shfl_xor(s, off);
                    const bool gt = s > 1.0f;
                    lo = gt ? tau : lo;
                    hi = gt ? hi : tau;
                }
                tau = 0.5f * (lo + hi);
                float ssum = 0.0f;
                for (int cc2 = lane; cc2 < TT; cc2 += 64) {
                    const float tt2 = fmaxf(fbz[cc2] - tau, 0.0f);
                    ssum = fmaf(tt2, tt2, ssum);
                }
                #pragma unroll
                for (int off = 32; off; off >>= 1) ssum += __shfl_xor(ssum, off);
                const float inv = 1.0f / ssum;
                const int d4 = lane * 4;
                float4 o = make_float4(0.f, 0.f, 0.f, 0.f);
                for (int s = 0; s < TT; ++s) {
                    const float tt2 = fmaxf(fbz[s] - tau, 0.0f);
                    const float w = tt2 * tt2 * inv;
                    if (w > 0.0f) {
                        const float4 v = *(const float4*)(V + ((size_t)b * TT + s) * DD + d4);
                        o.x = fmaf(w, v.x, o.x); o.y = fmaf(w, v.y, o.y);
                        o.z = fmaf(w, v.z, o.z); o.w = fmaf(w, v.w, o.w);
                    }
                }
                *(float4*)(Out + ((size_t)(b * TT + t0 + r)) * DD + d4) = o;
                if (lane == 0) CNT[r] = -1;
                __threadfence_block();
            }
        }
        __syncthreads();
    }

    // ---------------- scalar per-lane tau + weights (lane r owns row wrow0+r) ----------------
    {
        const int myrow = wrow0 + (lane & 15);        // lanes 16+ duplicate (benign)
        const int nRaw = CNT[myrow];
        const int n = (nRaw < 0) ? 0 : (nRaw > CAP ? CAP : nRaw);
        float cvr[CAP];
        #pragma unroll
        for (int i = 0; i < CAP; ++i)
            cvr[i] = (i < n) ? CVAL[myrow * CAP + i] : -3.0e30f;
        float emax = cvr[0];
        #pragma unroll
        for (int i = 1; i < CAP; ++i) emax = fmaxf(emax, cvr[i]);
        float lo = emax - 1.0f, hi = emax;
        for (int it = 0; it < NITER; ++it) {
            const float tau = 0.5f * (lo + hi);
            float s = 0.0f;
            #pragma unroll
            for (int i = 0; i < CAP; ++i) {
                const float tt2 = fmaxf(cvr[i] - tau, 0.0f);
                s = fmaf(tt2, tt2, s);
            }
            const bool gt = s > 1.0f;
            lo = gt ? tau : lo;
            hi = gt ? hi : tau;
        }
        const float tau = 0.5f * (lo + hi);
        float ssum = 0.0f;
        #pragma unroll
        for (int i = 0; i < CAP; ++i) {
            const float tt2 = fmaxf(cvr[i] - tau, 0.0f);
            ssum = fmaf(tt2, tt2, ssum);
        }
        const float inv = 1.0f / ssum;                // valid rows: ssum > 0
        if (lane < 16 && n > 0) {
            for (int i = 0; i < n; ++i) {
                const float tt2 = fmaxf(cvr[i] - tau, 0.0f);
                CVAL[myrow * CAP + i] = tt2 * tt2 * inv;   // normalized weight
            }
        }
    }

    // ---------------- sparse PV via broadcast LDS reads ----------------
    const float* Vb = V + (size_t)b * TT * DD;
    for (int j = 0; j < 16; ++j) {
        const int row = wrow0 + j;
        const int n = CNT[row];
        if (n < 0) continue;                   // slow path handled
        const int d4 = lane * 4;
        float4 o = make_float4(0.f, 0.f, 0.f, 0.f);
        for (int i = 0; i < n; ++i) {
            const float wi = CVAL[row * CAP + i];    // LDS broadcast (uniform addr)
            if (wi > 0.0f) {
                const int si = (int)CIDX[row * CAP + i];
                const float4 v = *(const float4*)(Vb + (size_t)si * DD + d4);
                o.x = fmaf(wi, v.x, o.x); o.y = fmaf(wi, v.y, o.y);
                o.z = fmaf(wi, v.z, o.z); o.w = fmaf(wi, v.w, o.w);
            }
        }
        *(float4*)(Out + ((size_t)(b * TT + t0 + row)) * DD + d4) = o;
    }
}

// ---------------- round-1 kernel kept as ws-size fallback ----------------
#define DOT4(A, Kv, Qv) \
    A = fmaf((Qv).x, (Kv).x, fmaf((Qv).y, (Kv).y, fmaf((Qv).z, (Kv).z, fmaf((Qv).w, (Kv).w, (A)))))

__launch_bounds__(256, 2)
__global__ void entmax_fallback_kernel(const float* __restrict__ Q,
                                       const float* __restrict__ V,
                                       const float* __restrict__ K,
                                       float* __restrict__ Out) {
    extern __shared__ float zshf[];
    const int tid = threadIdx.x;
    const int b   = blockIdx.x >> 8;
    const int t0  = (blockIdx.x & 255) * 8;
    const float* Qb = Q + ((size_t)b * TT + t0) * DD;
    const float* Kb = K + (size_t)b * TT * DD;
    const float* Vb = V + (size_t)b * TT * DD;
    for (int g = 0; g < 2; ++g) {
        const int c0 = (g << 10) + tid;
        const float* k0 = Kb + (size_t)c0 * DD;
        float4 acc[8];
        #pragma unroll
        for (int r = 0; r < 8; ++r) acc[r] = make_float4(0.f, 0.f, 0.f, 0.f);
        for (int d = 0; d < DD; d += 4) {
            const float4 ka = *(const float4*)(k0 + d);
            const float4 kb = *(const float4*)(k0 + 256 * DD + d);
            const float4 kc = *(const float4*)(k0 + 512 * DD + d);
            const float4 kd = *(const float4*)(k0 + 768 * DD + d);
            #pragma unroll
            for (int r = 0; r < 8; ++r) {
                const float4 qv = *(const float4*)(Qb + r * DD + d);
                DOT4(acc[r].x, ka, qv); DOT4(acc[r].y, kb, qv);
                DOT4(acc[r].z, kc, qv); DOT4(acc[r].w, kd, qv);
            }
        }
        #pragma unroll
        for (int r = 0; r < 8; ++r) {
            zshf[r * TT + c0      ] = 0.5f * acc[r].x;
            zshf[r * TT + c0 + 256] = 0.5f * acc[r].y;
            zshf[r * TT + c0 + 512] = 0.5f * acc[r].z;
            zshf[r * TT + c0 + 768] = 0.5f * acc[r].w;
        }
    }
    __syncthreads();
    {
        const int wid = tid >> 6, lane = tid & 63;
        for (int rr = 0; rr < 2; ++rr) {
            const int r = wid * 2 + rr;
            float* z = zshf + r * TT;
            float zv[32];
            float m = -3.402823466e38f;
            #pragma unroll
            for (int j = 0; j < 32; ++j) { zv[j] = z[lane + (j << 6)]; m = fmaxf(m, zv[j]); }
            #pragma unroll
            for (int off = 32; off; off >>= 1) m = fmaxf(m, __shfl_xor(m, off));
            float lo = m - 1.0f, hi = m;
            for (int it = 0; it < NITER; ++it) {
                const float tau = 0.5f * (lo + hi);
                float s = 0.f;
                #pragma unroll
                for (int j = 0; j < 32; ++j) { float t = fmaxf(zv[j] - tau, 0.f); s = fmaf(t, t, s); }
                #pragma unroll
                for (int off = 32; off; off >>= 1) s += __shfl_xor(s, off);
                const bool gt = (s - 1.0f) > 0.0f;
                lo = gt ? tau : lo; hi = gt ? hi : tau;
            }
            const float tau = 0.5f * (lo + hi);
            float ssum = 0.f;
            #pragma unroll
            for (int j = 0; j < 32; ++j) { float t = fmaxf(zv[j] - tau, 0.f); ssum = fmaf(t, t, ssum); }
            #pragma unroll
            for (int off = 32; off; off >>= 1) ssum += __shfl_xor(ssum, off);
            const float inv = 1.0f / ssum;
            #pragma unroll
            for (int j = 0; j < 32; ++j) {
                float t = fmaxf(zv[j] - tau, 0.f);
                z[lane + (j << 6)] = t * t * inv;
            }
        }
    }
    __syncthreads();
    {
        const int d2 = (tid & 127) * 2;
        const int sg = tid >> 7;
        float2 acc[8];
        #pragma unroll
        for (int r = 0; r < 8; ++r) acc[r] = make_float2(0.f, 0.f);
        for (int sc = 0; sc < TT; sc += 8) {
            const int s0 = sc + sg * 4;
            float4 w4[8];
            #pragma unroll
            for (int r = 0; r < 8; ++r) w4[r] = *(const float4*)&zshf[r * TT + s0];
            #pragma unroll
            for (int js = 0; js < 4; ++js) {
                const float2 v = *(const float2*)(Vb + (size_t)(s0 + js) * DD + d2);
                #pragma unroll
                for (int r = 0; r < 8; ++r) {
                    const float wv = (js == 0) ? w4[r].x : (js == 1) ? w4[r].y
                                   : (js == 2) ? w4[r].z : w4[r].w;
                    acc[r].x = fmaf(wv, v.x, acc[r].x);
                    acc[r].y = fmaf(wv, v.y, acc[r].y);
                }
            }
        }
        __syncthreads();
        float* part = zshf;
        if (sg == 1) {
            #pragma unroll
            for (int r = 0; r < 8; ++r) *(float2*)&part[r * DD + d2] = acc[r];
        }
        __syncthreads();
        if (sg == 0) {
            #pragma unroll
            for (int r = 0; r < 8; ++r) {
                const float2 p = *(const float2*)&part[r * DD + d2];
                float2 o; o.x = acc[r].x + p.x; o.y = acc[r].y + p.y;
                *(float2*)&Out[((size_t)b * TT + t0 + r) * DD + d2] = o;
            }
        }
    }
}

extern "C" void kernel_launch(void* const* d_in, const int* in_sizes, int n_in,
                              void* d_out, int out_size, void* d_ws, size_t ws_size,
                              hipStream_t stream) {
    const float* Q = (const float*)d_in[0];   // query
    const float* V = (const float*)d_in[1];   // value (dict order!)
    const float* K = (const float*)d_in[2];   // key
    float* Out = (float*)d_out;
    const int B = in_sizes[0] / (TT * DD);
    const size_t NE = (size_t)B * TT * DD;
    const size_t need = NE * 2;               // Kh bf16

    if (ws_size < need) {                     // defensive fallback (round-1 kernel)
        entmax_fallback_kernel<<<dim3(B * (TT / 8)), 256, 8 * TT * sizeof(float), stream>>>(
            Q, V, K, Out);
        return;
    }

    unsigned short* Kh = (unsigned short*)d_ws;
    split_k_kernel<<<2048, 256, 0, stream>>>(K, Kh, (int)(NE / 4));

    const int nwg = B * (TT / RQB);           // 1024 for B=16 -> 4 blocks/CU
    (void)hipFuncSetAttribute((const void*)entmax_screen_kernel,
                              hipFuncAttributeMaxDynamicSharedMemorySize, LDS_SZ);
    entmax_screen_kernel<<<dim3(nwg), NT, LDS_SZ, stream>>>(Q, Kh, K, V, Out, nwg);
}

// Round 10
// 198.079 us; speedup vs baseline: 2.3407x; 2.3407x over previous
//
#include <hip/hip_runtime.h>

#define TT 2048     // sequence length
#define DD 256      // head dim
#define RQB 128     // q-rows per block (8 waves, each covering ALL rows on its col-range)
#define NT 512      // 8 waves
#define NITER 30
#define CAPW 6      // per-wave per-row candidate slots (E ~0.3)
#define CAP 24      // merged candidates per row (E ~2.3)
#define THR_SLACK 1.75f

// LDS byte layout: Q [128][512B] swizzled at 0 (dead after sweep2 -> fbz slow-path buffer)
#define L_GP   65536                      // f32 [8][128] gmax partials = 4 KB
#define L_THR  (L_GP + 4096)              // f32 [128]
#define L_CW   (L_THR + 512)              // int [8][128] per-wave counts = 4 KB
#define L_IW   (L_CW + 4096)              // u16 [8][128][CAPW] = 12 KB
#define L_CIDX (L_IW + 8 * 128 * CAPW * 2)   // u16 [128][CAP] = 6 KB
#define L_CVAL (L_CIDX + RQB * CAP * 2)   // f32 [128][CAP] = 12 KB
#define L_CNT  (L_CVAL + RQB * CAP * 4)   // int [128]
#define L_SLOT (L_CNT + RQB * 4)          // u16 [8][16*CAP] = 6 KB
#define L_OVF  (L_SLOT + 8 * 16 * CAP * 2)
#define LDS_SZ (L_OVF + 16)               // ~110 KB -> 1 block/CU (by design)

typedef __attribute__((ext_vector_type(4))) float f32x4;
typedef __attribute__((ext_vector_type(8))) short short8;

__device__ inline unsigned short f2bf(float x) {     // RTN fp32 -> bf16
    unsigned u = __float_as_uint(x);
    return (unsigned short)((u + 0x7fffu + ((u >> 16) & 1u)) >> 16);
}
__device__ inline float bf2f(unsigned short h) {
    return __uint_as_float((unsigned)h << 16);
}

// max over each 16-lane group via DPP (VALU-only)
__device__ __forceinline__ float dppmax16(float m) {
    int a = __builtin_amdgcn_update_dpp(__float_as_int(m), __float_as_int(m),
                                        0xB1, 0xF, 0xF, false);
    m = fmaxf(m, __int_as_float(a));
    a = __builtin_amdgcn_update_dpp(__float_as_int(m), __float_as_int(m),
                                    0x4E, 0xF, 0xF, false);
    m = fmaxf(m, __int_as_float(a));
    a = __builtin_amdgcn_update_dpp(__float_as_int(m), __float_as_int(m),
                                    0x141, 0xF, 0xF, false);
    m = fmaxf(m, __int_as_float(a));
    a = __builtin_amdgcn_update_dpp(__float_as_int(m), __float_as_int(m),
                                    0x140, 0xF, 0xF, false);
    m = fmaxf(m, __int_as_float(a));
    return m;
}

// ---------------- helper: K -> 0.5*K bf16 (screening operand) ----------------
__global__ __launch_bounds__(256) void split_k_kernel(const float* __restrict__ K,
        unsigned short* __restrict__ Kh, int n4) {
    int i = blockIdx.x * 256 + threadIdx.x;
    const int stride = gridDim.x * 256;
    for (; i < n4; i += stride) {
        float4 v = ((const float4*)K)[i];
        unsigned short h0 = f2bf(0.5f * v.x), h1 = f2bf(0.5f * v.y);
        unsigned short h2 = f2bf(0.5f * v.z), h3 = f2bf(0.5f * v.w);
        uint2 hv;
        hv.x = (unsigned)h0 | ((unsigned)h1 << 16);
        hv.y = (unsigned)h2 | ((unsigned)h3 << 16);
        ((uint2*)Kh)[i] = hv;
    }
}

// ---------------- main fused kernel (barrier-free sweeps) ----------------
__launch_bounds__(NT, 2)
__global__ void entmax_nobar_kernel(const float* __restrict__ Q,
                                    const unsigned short* __restrict__ Kh,
                                    const float* __restrict__ Kf,
                                    const float* __restrict__ V,
                                    float* __restrict__ Out,
                                    int nwg) {
    extern __shared__ char smem[];
    float*          GP   = (float*)(smem + L_GP);
    float*          THR  = (float*)(smem + L_THR);
    int*            CW   = (int*)(smem + L_CW);
    unsigned short* IW   = (unsigned short*)(smem + L_IW);
    unsigned short* CIDX = (unsigned short*)(smem + L_CIDX);
    float*          CVAL = (float*)(smem + L_CVAL);
    int*            CNT  = (int*)(smem + L_CNT);
    unsigned short* SLOT = (unsigned short*)(smem + L_SLOT);
    int*            POVF = (int*)(smem + L_OVF);

    const int tid = threadIdx.x;
    const int wid = tid >> 6, lane = tid & 63;
    const int l15 = lane & 15, ag = lane >> 4;
    const int wrow0 = wid * 16;              // tail ownership only

    // XCD-bijective swizzle (nwg = B*16 = 256)
    const int lb = (blockIdx.x & 7) * (nwg >> 3) + (blockIdx.x >> 3);
    const int b  = lb >> 4;
    const int t0 = (lb & 15) * RQB;

    const char* KhB = (const char*)(Kh + (size_t)b * TT * DD);

    // zero per-wave counts + flag
    ((int*)(smem + L_CW))[tid] = 0;
    ((int*)(smem + L_CW))[tid + 512] = 0;
    if (tid == 0) *POVF = 0;

    // ---- stage Q -> LDS bf16, XOR-swizzled (once; read-only afterwards) ----
    {
        const int qrow = tid >> 2, seg = tid & 3;
        const float* qsrc = Q + (size_t)(b * TT + t0 + qrow) * DD + seg * 64;
        char* qd = smem + qrow * 512;
        const int swr = (qrow & 7) << 4;
        #pragma unroll
        for (int j = 0; j < 8; ++j) {
            float4 f0 = *(const float4*)(qsrc + j * 8);
            float4 f1 = *(const float4*)(qsrc + j * 8 + 4);
            uint4 pk;
            pk.x = (unsigned)f2bf(f0.x) | ((unsigned)f2bf(f0.y) << 16);
            pk.y = (unsigned)f2bf(f0.z) | ((unsigned)f2bf(f0.w) << 16);
            pk.z = (unsigned)f2bf(f1.x) | ((unsigned)f2bf(f1.y) << 16);
            pk.w = (unsigned)f2bf(f1.z) | ((unsigned)f2bf(f1.w) << 16);
            *(uint4*)(qd + ((seg * 128 + j * 16) ^ swr)) = pk;
        }
    }
    __syncthreads();

    const unsigned long long grpmask = 0xFFFFULL << (ag * 16);
    const unsigned long long lowmask = (lane == 0) ? 0ULL : ((~0ULL) >> (64 - lane));
    const int colw0 = wid * 256;             // this wave's private K-column range
    const int sx = (l15 & 7) << 4;
    const char* qbase = smem + l15 * 512;

    float mr[32];
    #pragma unroll
    for (int i = 0; i < 32; ++i) mr[i] = -3.0e30f;

    // ---------------- sweep 1: row maxima (no barriers) ----------------
    for (int tc = 0; tc < 8; ++tc) {
        const char* kb0 = KhB + (size_t)(colw0 + tc * 32 + l15) * 512 + ag * 16;
        short8 Bf[2][8];
        #pragma unroll
        for (int ct = 0; ct < 2; ++ct)
            #pragma unroll
            for (int kk = 0; kk < 8; ++kk)
                Bf[ct][kk] = *(const short8*)(kb0 + ct * 8192 + kk * 64);
        #pragma unroll
        for (int rp = 0; rp < 4; ++rp) {
            f32x4 acc[2][2];
            #pragma unroll
            for (int rg = 0; rg < 2; ++rg)
                #pragma unroll
                for (int ct = 0; ct < 2; ++ct)
                    #pragma unroll
                    for (int r = 0; r < 4; ++r) acc[rg][ct][r] = 0.0f;
            #pragma unroll
            for (int kk = 0; kk < 8; ++kk) {
                const int kb = (kk * 64 + ag * 16) ^ sx;
                short8 a0 = *(const short8*)(qbase + (rp * 32) * 512 + kb);
                short8 a1 = *(const short8*)(qbase + (rp * 32 + 16) * 512 + kb);
                acc[0][0] = __builtin_amdgcn_mfma_f32_16x16x32_bf16(a0, Bf[0][kk], acc[0][0], 0, 0, 0);
                acc[0][1] = __builtin_amdgcn_mfma_f32_16x16x32_bf16(a0, Bf[1][kk], acc[0][1], 0, 0, 0);
                acc[1][0] = __builtin_amdgcn_mfma_f32_16x16x32_bf16(a1, Bf[0][kk], acc[1][0], 0, 0, 0);
                acc[1][1] = __builtin_amdgcn_mfma_f32_16x16x32_bf16(a1, Bf[1][kk], acc[1][1], 0, 0, 0);
            }
            #pragma unroll
            for (int rg = 0; rg < 2; ++rg)
                #pragma unroll
                for (int r = 0; r < 4; ++r)
                    mr[rp * 8 + rg * 4 + r] = fmaxf(mr[rp * 8 + rg * 4 + r],
                                                    fmaxf(acc[rg][0][r], acc[rg][1][r]));
        }
    }
    // publish per-wave row maxima
    #pragma unroll
    for (int rp = 0; rp < 4; ++rp)
        #pragma unroll
        for (int rg = 0; rg < 2; ++rg)
            #pragma unroll
            for (int r = 0; r < 4; ++r) {
                const float m = dppmax16(mr[rp * 8 + rg * 4 + r]);
                if (l15 == 0)
                    GP[wid * 128 + rp * 32 + rg * 16 + ag * 4 + r] = m;
            }
    __syncthreads();
    if (tid < 128) {
        float m = GP[tid];
        #pragma unroll
        for (int w = 1; w < 8; ++w) m = fmaxf(m, GP[w * 128 + tid]);
        THR[tid] = m - THR_SLACK;
    }
    __syncthreads();

    // preload this lane's row thresholds into mr
    #pragma unroll
    for (int rp = 0; rp < 4; ++rp)
        #pragma unroll
        for (int rg = 0; rg < 2; ++rg)
            #pragma unroll
            for (int r = 0; r < 4; ++r)
                mr[rp * 8 + rg * 4 + r] = THR[rp * 32 + rg * 16 + ag * 4 + r];

    // ---------------- sweep 2: recompute + append (no barriers) ----------------
    for (int tc = 0; tc < 8; ++tc) {
        const char* kb0 = KhB + (size_t)(colw0 + tc * 32 + l15) * 512 + ag * 16;
        short8 Bf[2][8];
        #pragma unroll
        for (int ct = 0; ct < 2; ++ct)
            #pragma unroll
            for (int kk = 0; kk < 8; ++kk)
                Bf[ct][kk] = *(const short8*)(kb0 + ct * 8192 + kk * 64);
        #pragma unroll
        for (int rp = 0; rp < 4; ++rp) {
            f32x4 acc[2][2];
            #pragma unroll
            for (int rg = 0; rg < 2; ++rg)
                #pragma unroll
                for (int ct = 0; ct < 2; ++ct)
                    #pragma unroll
                    for (int r = 0; r < 4; ++r) acc[rg][ct][r] = 0.0f;
            #pragma unroll
            for (int kk = 0; kk < 8; ++kk) {
                const int kb = (kk * 64 + ag * 16) ^ sx;
                short8 a0 = *(const short8*)(qbase + (rp * 32) * 512 + kb);
                short8 a1 = *(const short8*)(qbase + (rp * 32 + 16) * 512 + kb);
                acc[0][0] = __builtin_amdgcn_mfma_f32_16x16x32_bf16(a0, Bf[0][kk], acc[0][0], 0, 0, 0);
                acc[0][1] = __builtin_amdgcn_mfma_f32_16x16x32_bf16(a0, Bf[1][kk], acc[0][1], 0, 0, 0);
                acc[1][0] = __builtin_amdgcn_mfma_f32_16x16x32_bf16(a1, Bf[0][kk], acc[1][0], 0, 0, 0);
                acc[1][1] = __builtin_amdgcn_mfma_f32_16x16x32_bf16(a1, Bf[1][kk], acc[1][1], 0, 0, 0);
            }
            #pragma unroll
            for (int rg = 0; rg < 2; ++rg)
                #pragma unroll
                for (int r = 0; r < 4; ++r) {
                    const float thrv = mr[rp * 8 + rg * 4 + r];
                    const int row = rp * 32 + rg * 16 + ag * 4 + r;
                    #pragma unroll
                    for (int ct = 0; ct < 2; ++ct) {
                        const bool p = acc[rg][ct][r] > thrv;
                        const unsigned long long ball = __ballot(p) & grpmask;
                        if (ball) {                       // rare (~35 events/wave)
                            const int cnt = (int)__popcll(ball);
                            const int rank = (int)__popcll(ball & lowmask);
                            const int base = CW[wid * 128 + row];
                            if (p && base + rank < CAPW)
                                IW[(wid * 128 + row) * CAPW + base + rank] =
                                    (unsigned short)(colw0 + tc * 32 + ct * 16 + l15);
                            if (l15 == 0) CW[wid * 128 + row] = base + cnt;
                        }
                    }
                }
        }
    }
    __syncthreads();

    // ---------------- merge per-wave lists (each wave its 16 tail rows) ----------------
    if (lane < 16) {
        const int row = wrow0 + lane;
        int n = 0, ovf = 0;
        for (int w = 0; w < 8; ++w) {
            int cw = CW[w * 128 + row];
            if (cw > CAPW) { ovf = 1; cw = CAPW; }
            for (int i = 0; i < cw; ++i) {
                if (n < CAP) CIDX[row * CAP + n] = IW[(w * 128 + row) * CAPW + i];
                ++n;
            }
        }
        if (n > CAP) ovf = 1;
        CNT[row] = ovf ? (CAP + 1) : n;      // CAP+1 = slow-path sentinel
        if (ovf) *POVF = 1;
    }

    // ---------------- exact fp32 recompute of merged candidates ----------------
    int c = 0;
    if (lane < 16) {
        const int cc = CNT[wrow0 + lane];
        c = (cc > CAP) ? 0 : cc;             // overflow rows -> slow path, skip here
    }
    int x = c;
    #pragma unroll
    for (int off = 1; off < 16; off <<= 1) {
        const int v = __shfl_up(x, off);
        if ((lane & 15) >= off) x += v;
    }
    const int pfx = x - c;
    const int total = __shfl(x, 15);
    if (lane < 16)
        for (int i = 0; i < c; ++i)
            SLOT[wid * (16 * CAP) + pfx + i] = (unsigned short)((lane << 8) | i);

    {
        const float* Qb = Q + (size_t)(b * TT + t0 + wrow0) * DD;
        const float* Kb = Kf + (size_t)b * TT * DD;
        for (int bs = 0; bs < total; bs += 8) {
            float4 qv[8], kv[8];
            int rl[8], ii[8];
            #pragma unroll
            for (int u = 0; u < 8; ++u) {
                const int s = bs + u;
                const int e = (s < total) ? (int)SLOT[wid * (16 * CAP) + s] : 0;
                rl[u] = e >> 8; ii[u] = e & 255;
                const int col = (s < total) ? (int)CIDX[(wrow0 + rl[u]) * CAP + ii[u]] : 0;
                qv[u] = *(const float4*)(Qb + (size_t)rl[u] * DD + lane * 4);
                kv[u] = *(const float4*)(Kb + (size_t)col * DD + lane * 4);
            }
            float sm[8];
            #pragma unroll
            for (int u = 0; u < 8; ++u) {
                float d = qv[u].x * kv[u].x;
                d = fmaf(qv[u].y, kv[u].y, d);
                d = fmaf(qv[u].z, kv[u].z, d);
                d = fmaf(qv[u].w, kv[u].w, d);
                sm[u] = d;
            }
            #pragma unroll
            for (int off = 32; off; off >>= 1)
                #pragma unroll
                for (int u = 0; u < 8; ++u) sm[u] += __shfl_xor(sm[u], off);
            #pragma unroll
            for (int u = 0; u < 8; ++u)
                if (lane == u && bs + u < total)
                    CVAL[(wrow0 + rl[u]) * CAP + ii[u]] = 0.5f * sm[u];
        }
    }
    __syncthreads();

    // ---------------- slow path (overflow; ~never) ----------------
    if (*POVF) {
        if (wid == 0) {
            float* fbz = (float*)smem;       // Q region is dead now
            for (int r = 0; r < RQB; ++r) {
                if (CNT[r] <= CAP) continue;
                const float* qr = Q + (size_t)(b * TT + t0 + r) * DD;
                const float* Kb = Kf + (size_t)b * TT * DD;
                for (int cc2 = lane; cc2 < TT; cc2 += 64) {
                    const float* kr = Kb + (size_t)cc2 * DD;
                    float a = 0.0f;
                    for (int d = 0; d < DD; ++d) a = fmaf(qr[d], kr[d], a);
                    fbz[cc2] = 0.5f * a;
                }
                __threadfence_block();
                float m = -3.402823466e38f;
                for (int cc2 = lane; cc2 < TT; cc2 += 64) m = fmaxf(m, fbz[cc2]);
                #pragma unroll
                for (int off = 32; off; off >>= 1) m = fmaxf(m, __shfl_xor(m, off));
                float lo = m - 1.0f, hi = m, tau;
                for (int it = 0; it < NITER; ++it) {
                    tau = 0.5f * (lo + hi);
                    float s = 0.0f;
                    for (int cc2 = lane; cc2 < TT; cc2 += 64) {
                        const float tt2 = fmaxf(fbz[cc2] - tau, 0.0f);
                        s = fmaf(tt2, tt2, s);
                    }
                    #pragma unroll
                    for (int off = 32; off; off >>= 1) s += __shfl_xor(s, off);
                    const bool gt = s > 1.0f;
                    lo = gt ? tau : lo;
                    hi = gt ? hi : tau;
                }
                tau = 0.5f * (lo + hi);
                float ssum = 0.0f;
                for (int cc2 = lane; cc2 < TT; cc2 += 64) {
                    const float tt2 = fmaxf(fbz[cc2] - tau, 0.0f);
                    ssum = fmaf(tt2, tt2, ssum);
                }
                #pragma unroll
                for (int off = 32; off; off >>= 1) ssum += __shfl_xor(ssum, off);
                const float inv = 1.0f / ssum;
                const int d4 = lane * 4;
                float4 o = make_float4(0.f, 0.f, 0.f, 0.f);
                for (int s = 0; s < TT; ++s) {
                    const float tt2 = fmaxf(fbz[s] - tau, 0.0f);
                    const float w = tt2 * tt2 * inv;
                    if (w > 0.0f) {
                        const float4 v = *(const float4*)(V + ((size_t)b * TT + s) * DD + d4);
                        o.x = fmaf(w, v.x, o.x); o.y = fmaf(w, v.y, o.y);
                        o.z = fmaf(w, v.z, o.z); o.w = fmaf(w, v.w, o.w);
                    }
                }
                *(float4*)(Out + ((size_t)(b * TT + t0 + r)) * DD + d4) = o;
                if (lane == 0) CNT[r] = -1;
                __threadfence_block();
            }
        }
        __syncthreads();
    }

    // ---------------- scalar per-lane tau + weights ----------------
    {
        const int myrow = wrow0 + (lane & 15);
        const int nRaw = CNT[myrow];
        const int n = (nRaw < 0 || nRaw > CAP) ? 0 : nRaw;
        float cvr[CAP];
        #pragma unroll
        for (int i = 0; i < CAP; ++i)
            cvr[i] = (i < n) ? CVAL[myrow * CAP + i] : -3.0e30f;
        float emax = cvr[0];
        #pragma unroll
        for (int i = 1; i < CAP; ++i) emax = fmaxf(emax, cvr[i]);
        float lo = emax - 1.0f, hi = emax;
        for (int it = 0; it < NITER; ++it) {
            const float tau = 0.5f * (lo + hi);
            float s = 0.0f;
            #pragma unroll
            for (int i = 0; i < CAP; ++i) {
                const float tt2 = fmaxf(cvr[i] - tau, 0.0f);
                s = fmaf(tt2, tt2, s);
            }
            const bool gt = s > 1.0f;
            lo = gt ? tau : lo;
            hi = gt ? hi : tau;
        }
        const float tau = 0.5f * (lo + hi);
        float ssum = 0.0f;
        #pragma unroll
        for (int i = 0; i < CAP; ++i) {
            const float tt2 = fmaxf(cvr[i] - tau, 0.0f);
            ssum = fmaf(tt2, tt2, ssum);
        }
        const float inv = 1.0f / ssum;
        if (lane < 16 && n > 0) {
            for (int i = 0; i < n; ++i) {
                const float tt2 = fmaxf(cvr[i] - tau, 0.0f);
                CVAL[myrow * CAP + i] = tt2 * tt2 * inv;
            }
        }
    }

    // ---------------- sparse PV via broadcast LDS reads ----------------
    const float* Vb = V + (size_t)b * TT * DD;
    for (int j = 0; j < 16; ++j) {
        const int row = wrow0 + j;
        const int n = CNT[row];
        if (n < 0 || n > CAP) continue;      // slow path handled
        const int d4 = lane * 4;
        float4 o = make_float4(0.f, 0.f, 0.f, 0.f);
        for (int i = 0; i < n; ++i) {
            const float wi = CVAL[row * CAP + i];
            if (wi > 0.0f) {
                const int si = (int)CIDX[row * CAP + i];
                const float4 v = *(const float4*)(Vb + (size_t)si * DD + d4);
                o.x = fmaf(wi, v.x, o.x); o.y = fmaf(wi, v.y, o.y);
                o.z = fmaf(wi, v.z, o.z); o.w = fmaf(wi, v.w, o.w);
            }
        }
        *(float4*)(Out + ((size_t)(b * TT + t0 + row)) * DD + d4) = o;
    }
}

// ---------------- round-1 kernel kept as ws-size fallback ----------------
#define DOT4(A, Kv, Qv) \
    A = fmaf((Qv).x, (Kv).x, fmaf((Qv).y, (Kv).y, fmaf((Qv).z, (Kv).z, fmaf((Qv).w, (Kv).w, (A)))))

__launch_bounds__(256, 2)
__global__ void entmax_fallback_kernel(const float* __restrict__ Q,
                                       const float* __restrict__ V,
                                       const float* __restrict__ K,
                                       float* __restrict__ Out) {
    extern __shared__ float zshf[];
    const int tid = threadIdx.x;
    const int b   = blockIdx.x >> 8;
    const int t0  = (blockIdx.x & 255) * 8;
    const float* Qb = Q + ((size_t)b * TT + t0) * DD;
    const float* Kb = K + (size_t)b * TT * DD;
    const float* Vb = V + (size_t)b * TT * DD;
    for (int g = 0; g < 2; ++g) {
        const int c0 = (g << 10) + tid;
        const float* k0 = Kb + (size_t)c0 * DD;
        float4 acc[8];
        #pragma unroll
        for (int r = 0; r < 8; ++r) acc[r] = make_float4(0.f, 0.f, 0.f, 0.f);
        for (int d = 0; d < DD; d += 4) {
            const float4 ka = *(const float4*)(k0 + d);
            const float4 kb = *(const float4*)(k0 + 256 * DD + d);
            const float4 kc = *(const float4*)(k0 + 512 * DD + d);
            const float4 kd = *(const float4*)(k0 + 768 * DD + d);
            #pragma unroll
            for (int r = 0; r < 8; ++r) {
                const float4 qv = *(const float4*)(Qb + r * DD + d);
                DOT4(acc[r].x, ka, qv); DOT4(acc[r].y, kb, qv);
                DOT4(acc[r].z, kc, qv); DOT4(acc[r].w, kd, qv);
            }
        }
        #pragma unroll
        for (int r = 0; r < 8; ++r) {
            zshf[r * TT + c0      ] = 0.5f * acc[r].x;
            zshf[r * TT + c0 + 256] = 0.5f * acc[r].y;
            zshf[r * TT + c0 + 512] = 0.5f * acc[r].z;
            zshf[r * TT + c0 + 768] = 0.5f * acc[r].w;
        }
    }
    __syncthreads();
    {
        const int wid = tid >> 6, lane = tid & 63;
        for (int rr = 0; rr < 2; ++rr) {
            const int r = wid * 2 + rr;
            float* z = zshf + r * TT;
            float zv[32];
            float m = -3.402823466e38f;
            #pragma unroll
            for (int j = 0; j < 32; ++j) { zv[j] = z[lane + (j << 6)]; m = fmaxf(m, zv[j]); }
            #pragma unroll
            for (int off = 32; off; off >>= 1) m = fmaxf(m, __shfl_xor(m, off));
            float lo = m - 1.0f, hi = m;
            for (int it = 0; it < NITER; ++it) {
                const float tau = 0.5f * (lo + hi);
                float s = 0.f;
                #pragma unroll
                for (int j = 0; j < 32; ++j) { float t = fmaxf(zv[j] - tau, 0.f); s = fmaf(t, t, s); }
                #pragma unroll
                for (int off = 32; off; off >>= 1) s += __shfl_xor(s, off);
                const bool gt = (s - 1.0f) > 0.0f;
                lo = gt ? tau : lo; hi = gt ? hi : tau;
            }
            const float tau = 0.5f * (lo + hi);
            float ssum = 0.f;
            #pragma unroll
            for (int j = 0; j < 32; ++j) { float t = fmaxf(zv[j] - tau, 0.f); ssum = fmaf(t, t, ssum); }
            #pragma unroll
            for (int off = 32; off; off >>= 1) ssum += __shfl_xor(ssum, off);
            const float inv = 1.0f / ssum;
            #pragma unroll
            for (int j = 0; j < 32; ++j) {
                float t = fmaxf(zv[j] - tau, 0.f);
                z[lane + (j << 6)] = t * t * inv;
            }
        }
    }
    __syncthreads();
    {
        const int d2 = (tid & 127) * 2;
        const int sg = tid >> 7;
        float2 acc[8];
        #pragma unroll
        for (int r = 0; r < 8; ++r) acc[r] = make_float2(0.f, 0.f);
        for (int sc = 0; sc < TT; sc += 8) {
            const int s0 = sc + sg * 4;
            float4 w4[8];
            #pragma unroll
            for (int r = 0; r < 8; ++r) w4[r] = *(const float4*)&zshf[r * TT + s0];
            #pragma unroll
            for (int js = 0; js < 4; ++js) {
                const float2 v = *(const float2*)(Vb + (size_t)(s0 + js) * DD + d2);
                #pragma unroll
                for (int r = 0; r < 8; ++r) {
                    const float wv = (js == 0) ? w4[r].x : (js == 1) ? w4[r].y
                                   : (js == 2) ? w4[r].z : w4[r].w;
                    acc[r].x = fmaf(wv, v.x, acc[r].x);
                    acc[r].y = fmaf(wv, v.y, acc[r].y);
                }
            }
        }
        __syncthreads();
        float* part = zshf;
        if (sg == 1) {
            #pragma unroll
            for (int r = 0; r < 8; ++r) *(float2*)&part[r * DD + d2] = acc[r];
        }
        __syncthreads();
        if (sg == 0) {
            #pragma unroll
            for (int r = 0; r < 8; ++r) {
                const float2 p = *(const float2*)&part[r * DD + d2];
                float2 o; o.x = acc[r].x + p.x; o.y = acc[r].y + p.y;
                *(float2*)&Out[((size_t)b * TT + t0 + r) * DD + d2] = o;
            }
        }
    }
}

extern "C" void kernel_launch(void* const* d_in, const int* in_sizes, int n_in,
                              void* d_out, int out_size, void* d_ws, size_t ws_size,
                              hipStream_t stream) {
    const float* Q = (const float*)d_in[0];   // query
    const float* V = (const float*)d_in[1];   // value (dict order!)
    const float* K = (const float*)d_in[2];   // key
    float* Out = (float*)d_out;
    const int B = in_sizes[0] / (TT * DD);
    const size_t NE = (size_t)B * TT * DD;
    const size_t need = NE * 2;               // Kh bf16

    if (ws_size < need) {                     // defensive fallback (round-1 kernel)
        entmax_fallback_kernel<<<dim3(B * (TT / 8)), 256, 8 * TT * sizeof(float), stream>>>(
            Q, V, K, Out);
        return;
    }

    unsigned short* Kh = (unsigned short*)d_ws;
    split_k_kernel<<<2048, 256, 0, stream>>>(K, Kh, (int)(NE / 4));

    const int nwg = B * (TT / RQB);           // 256 -> 1 block/CU, 8 waves
    (void)hipFuncSetAttribute((const void*)entmax_nobar_kernel,
                              hipFuncAttributeMaxDynamicSharedMemorySize, LDS_SZ);
    entmax_nobar_kernel<<<dim3(nwg), NT, LDS_SZ, stream>>>(Q, Kh, K, V, Out, nwg);
}

// Round 12
// 174.611 us; speedup vs baseline: 2.6553x; 1.1344x over previous
//
#include <hip/hip_runtime.h>

#define TT 2048     // sequence length
#define DD 256      // head dim
#define RQB 128     // q-rows per block (4 row-groups x 32 rows, x2 col-halves = 8 waves)
#define NT 512      // 8 waves
#define NITER 30
#define CAPW 24     // per-wave per-row candidate slots (E ~7-12 per 1024-col half)
#define CAP 48      // merged (2 x CAPW)
#define SLACK 1.6f

// LDS: tables only (~70 KB). FBZ = slow-path row buffer.
#define L_FBZ  0                             // f32 [2048] = 8 KB
#define L_CW   8192                          // int [8][32] = 1 KB
#define L_IW   (L_CW + 1024)                 // u16 [8][32][CAPW] = 12 KB
#define L_CIDX (L_IW + 8 * 32 * CAPW * 2)    // u16 [128][CAP] = 12 KB
#define L_CVAL (L_CIDX + RQB * CAP * 2)      // f32 [128][CAP] = 24 KB
#define L_CNT  (L_CVAL + RQB * CAP * 4)      // int [128]
#define L_SLOT (L_CNT + RQB * 4)             // u16 [8][16*CAP] = 12 KB
#define L_OVF  (L_SLOT + 8 * 16 * CAP * 2)
#define LDS_SZ (L_OVF + 16)                  // ~71 KB -> 1 block/CU (grid 256)

typedef __attribute__((ext_vector_type(4))) float f32x4;
typedef __attribute__((ext_vector_type(8))) short short8;

__device__ inline unsigned short f2bf(float x) {     // RTN fp32 -> bf16
    unsigned u = __float_as_uint(x);
    return (unsigned short)((u + 0x7fffu + ((u >> 16) & 1u)) >> 16);
}

// max over each 16-lane group via DPP (VALU-only)
__device__ __forceinline__ float dppmax16(float m) {
    int a = __builtin_amdgcn_update_dpp(__float_as_int(m), __float_as_int(m),
                                        0xB1, 0xF, 0xF, false);   // quad_perm [1,0,3,2]
    m = fmaxf(m, __int_as_float(a));
    a = __builtin_amdgcn_update_dpp(__float_as_int(m), __float_as_int(m),
                                    0x4E, 0xF, 0xF, false);       // quad_perm [2,3,0,1]
    m = fmaxf(m, __int_as_float(a));
    a = __builtin_amdgcn_update_dpp(__float_as_int(m), __float_as_int(m),
                                    0x141, 0xF, 0xF, false);      // row_half_mirror
    m = fmaxf(m, __int_as_float(a));
    a = __builtin_amdgcn_update_dpp(__float_as_int(m), __float_as_int(m),
                                    0x140, 0xF, 0xF, false);      // row_mirror
    m = fmaxf(m, __int_as_float(a));
    return m;
}

// ---------------- pack K into MFMA-fragment order (0.5*K bf16) ----------------
// Khf 16B chunk t = [b][g][kk][lane]: holds K[b][g*16+(lane&15)][kk*32+(lane>>4)*8 .. +8]
__global__ __launch_bounds__(256) void pack_k_kernel(const float* __restrict__ K,
        unsigned short* __restrict__ Khf) {
    const int t = blockIdx.x * 256 + threadIdx.x;
    const int lane = t & 63;
    const int kk = (t >> 6) & 7;
    const int g  = (t >> 9) & 127;
    const int b  = t >> 16;
    const int col = g * 16 + (lane & 15);
    const int d0  = kk * 32 + (lane >> 4) * 8;
    const float* src = K + ((size_t)b * TT + col) * DD + d0;
    const float4 f0 = *(const float4*)(src);
    const float4 f1 = *(const float4*)(src + 4);
    uint4 pk;
    pk.x = (unsigned)f2bf(0.5f * f0.x) | ((unsigned)f2bf(0.5f * f0.y) << 16);
    pk.y = (unsigned)f2bf(0.5f * f0.z) | ((unsigned)f2bf(0.5f * f0.w) << 16);
    pk.z = (unsigned)f2bf(0.5f * f1.x) | ((unsigned)f2bf(0.5f * f1.y) << 16);
    pk.w = (unsigned)f2bf(0.5f * f1.z) | ((unsigned)f2bf(0.5f * f1.w) << 16);
    *(uint4*)(Khf + (size_t)t * 8) = pk;
}

// ---------------- main fused kernel (barrier-free sweep) ----------------
#define LOADB(B_, g_) do { \
    _Pragma("unroll") for (int kk_ = 0; kk_ < 8; ++kk_) \
        B_[kk_] = *(const short8*)(KfB + ((size_t)((Gbase + (g_)) * 8 + kk_) << 10) + lane * 16); \
    } while (0)

#define PROCF(B_, aA_, aB_) do { \
    _Pragma("unroll") for (int r_ = 0; r_ < 4; ++r_) { aA_[r_] = 0.0f; aB_[r_] = 0.0f; } \
    _Pragma("unroll") for (int kk_ = 0; kk_ < 8; ++kk_) { \
        aA_ = __builtin_amdgcn_mfma_f32_16x16x32_bf16(ah0[kk_], B_[kk_], aA_, 0, 0, 0); \
        aB_ = __builtin_amdgcn_mfma_f32_16x16x32_bf16(ah1[kk_], B_[kk_], aB_, 0, 0, 0); \
    } } while (0)

__launch_bounds__(NT, 2)
__global__ void entmax_frag_kernel(const float* __restrict__ Q,
                                   const unsigned short* __restrict__ Khf,
                                   const float* __restrict__ Kf,
                                   const float* __restrict__ V,
                                   float* __restrict__ Out,
                                   int nwg) {
    extern __shared__ char smem[];
    int*            CW   = (int*)(smem + L_CW);
    unsigned short* IW   = (unsigned short*)(smem + L_IW);
    unsigned short* CIDX = (unsigned short*)(smem + L_CIDX);
    float*          CVAL = (float*)(smem + L_CVAL);
    int*            CNT  = (int*)(smem + L_CNT);
    unsigned short* SLOT = (unsigned short*)(smem + L_SLOT);
    int*            POVF = (int*)(smem + L_OVF);

    const int tid = threadIdx.x;
    const int wid = tid >> 6, lane = tid & 63;
    const int l15 = lane & 15, ag = lane >> 4;
    const int rg = wid >> 1, cg = wid & 1;   // row-group (32 rows), col-half (1024 cols)
    const int wrow0 = wid * 16;              // tail ownership

    // XCD-bijective swizzle (nwg = B*16 = 256)
    const int lb = (blockIdx.x & 7) * (nwg >> 3) + (blockIdx.x >> 3);
    const int b  = lb >> 4;
    const int t0 = (lb & 15) * RQB;

    const char* KfB = (const char*)Khf + (size_t)b * 1048576;   // 128 g x 8 kk x 1024 B
    const int Gbase = cg * 64;
    const int colw0 = cg * 1024;

    if (lane < 32) CW[wid * 32 + lane] = 0;
    if (tid == 0) *POVF = 0;

    // ---- A-fragments: 32 rows per wave in VGPRs (rows rg*32 .. +32) ----
    short8 ah0[8], ah1[8];
    {
        const float* q0 = Q + (size_t)(b * TT + t0 + rg * 32 + l15) * DD;
        const float* q1 = q0 + 16 * DD;
        #pragma unroll
        for (int kk = 0; kk < 8; ++kk) {
            const int d0 = kk * 32 + ag * 8;
            float4 a = *(const float4*)(q0 + d0);
            float4 c = *(const float4*)(q0 + d0 + 4);
            float qf[8] = {a.x, a.y, a.z, a.w, c.x, c.y, c.z, c.w};
            #pragma unroll
            for (int i = 0; i < 8; ++i) ah0[kk][i] = (short)f2bf(qf[i]);
            a = *(const float4*)(q1 + d0);
            c = *(const float4*)(q1 + d0 + 4);
            float qg[8] = {a.x, a.y, a.z, a.w, c.x, c.y, c.z, c.w};
            #pragma unroll
            for (int i = 0; i < 8; ++i) ah1[kk][i] = (short)f2bf(qg[i]);
        }
    }

    const unsigned long long grpmask = 0xFFFFULL << (ag * 16);
    const unsigned long long lowmask = (lane == 0) ? 0ULL : ((~0ULL) >> (64 - lane));
    float rm0[4], rm1[4];
    int   bs0[4], bs1[4];
    #pragma unroll
    for (int r = 0; r < 4; ++r) {
        rm0[r] = -3.0e30f; rm1[r] = -3.0e30f;
        bs0[r] = 0; bs1[r] = 0;
    }

    // screen 4 chunk-accumulators for one 16-row fragment set (lambda: real scoping)
    auto screen4 = [&](float (&rm)[4], int (&bs)[4], int fof,
                       const f32x4& x0, const f32x4& x1,
                       const f32x4& x2, const f32x4& x3, int c0) {
        #pragma unroll
        for (int r = 0; r < 4; ++r) {
            float m = fmaxf(fmaxf(x0[r], x1[r]), fmaxf(x2[r], x3[r]));
            m = dppmax16(m);                     // uniform within 16-lane group
            rm[r] = fmaxf(rm[r], m);
            const float thr = rm[r] - SLACK;
            if (m > thr) {                       // group-uniform early-out
                const int lrow = wid * 32 + fof + ag * 4 + r;
                const float vals[4] = {x0[r], x1[r], x2[r], x3[r]};
                #pragma unroll
                for (int ch = 0; ch < 4; ++ch) {
                    const bool p = vals[ch] > thr;
                    const unsigned long long ba = __ballot(p) & grpmask;
                    if (ba) {
                        const int rk = (int)__popcll(ba & lowmask);
                        if (p && bs[r] + rk < CAPW)
                            IW[lrow * CAPW + bs[r] + rk] =
                                (unsigned short)(colw0 + (c0 + ch) * 16 + l15);
                        bs[r] += (int)__popcll(ba);
                    }
                }
            }
        }
    };

    // ---------------- barrier-free sweep: 16 groups x 4 chunks x 16 cols ----------------
    short8 B0[8], B1[8];
    for (int j = 0; j < 16; ++j) {
        const int c0 = j * 4;
        f32x4 a0A, a0B, a1A, a1B, a2A, a2B, a3A, a3B;
        LOADB(B0, c0);
        LOADB(B1, c0 + 1);
        PROCF(B0, a0A, a0B);
        LOADB(B0, c0 + 2);
        PROCF(B1, a1A, a1B);
        LOADB(B1, c0 + 3);
        PROCF(B0, a2A, a2B);
        PROCF(B1, a3A, a3B);
        screen4(rm0, bs0, 0,  a0A, a1A, a2A, a3A, c0);
        screen4(rm1, bs1, 16, a0B, a1B, a2B, a3B, c0);
    }

    // publish per-wave counts
    if (l15 == 0) {
        #pragma unroll
        for (int r = 0; r < 4; ++r) {
            CW[wid * 32 + ag * 4 + r]      = bs0[r];
            CW[wid * 32 + 16 + ag * 4 + r] = bs1[r];
        }
    }
    __syncthreads();

    // ---------------- merge the 2 col-halves' lists (tail wave owns 16 rows) ----------------
    if (lane < 16) {
        const int row = wrow0 + lane;
        const int lr = row & 31;
        const int w0 = (row >> 5) * 2;
        int n = 0, ovf = 0;
        #pragma unroll
        for (int wv = 0; wv < 2; ++wv) {
            int cw = CW[(w0 + wv) * 32 + lr];
            if (cw > CAPW) { ovf = 1; cw = CAPW; }
            for (int i = 0; i < cw; ++i)
                CIDX[row * CAP + (n++)] = IW[((w0 + wv) * 32 + lr) * CAPW + i];
        }
        CNT[row] = ovf ? (CAP + 1) : n;
        if (ovf) *POVF = 1;
    }
    __syncthreads();

    // ---------------- exact fp32 recompute of merged candidates ----------------
    int c = 0;
    if (lane < 16) {
        const int cc = CNT[wrow0 + lane];
        c = (cc > CAP) ? 0 : cc;             // overflow rows -> slow path
    }
    int x = c;
    #pragma unroll
    for (int off = 1; off < 16; off <<= 1) {
        const int v = __shfl_up(x, off);
        if ((lane & 15) >= off) x += v;
    }
    const int pfx = x - c;
    const int total = __shfl(x, 15);
    if (lane < 16)
        for (int i = 0; i < c; ++i)
            SLOT[wid * (16 * CAP) + pfx + i] = (unsigned short)((lane << 8) | i);

    {
        const float* Qb = Q + (size_t)(b * TT + t0 + wrow0) * DD;
        const float* Kb = Kf + (size_t)b * TT * DD;
        for (int bsx = 0; bsx < total; bsx += 8) {
            float4 qv[8], kv[8];
            int rl[8], ii[8];
            #pragma unroll
            for (int u = 0; u < 8; ++u) {
                const int s = bsx + u;
                const int e = (s < total) ? (int)SLOT[wid * (16 * CAP) + s] : 0;
                rl[u] = e >> 8; ii[u] = e & 255;
                const int col = (s < total) ? (int)CIDX[(wrow0 + rl[u]) * CAP + ii[u]] : 0;
                qv[u] = *(const float4*)(Qb + (size_t)rl[u] * DD + lane * 4);
                kv[u] = *(const float4*)(Kb + (size_t)col * DD + lane * 4);
            }
            float sm[8];
            #pragma unroll
            for (int u = 0; u < 8; ++u) {
                float d = qv[u].x * kv[u].x;
                d = fmaf(qv[u].y, kv[u].y, d);
                d = fmaf(qv[u].z, kv[u].z, d);
                d = fmaf(qv[u].w, kv[u].w, d);
                sm[u] = d;
            }
            #pragma unroll
            for (int off = 32; off; off >>= 1)
                #pragma unroll
                for (int u = 0; u < 8; ++u) sm[u] += __shfl_xor(sm[u], off);
            #pragma unroll
            for (int u = 0; u < 8; ++u)
                if (lane == u && bsx + u < total)
                    CVAL[(wrow0 + rl[u]) * CAP + ii[u]] = 0.5f * sm[u];
        }
    }
    __syncthreads();

    // ---------------- slow path (CAPW overflow; ~never) ----------------
    if (*POVF) {
        if (wid == 0) {
            float* fbz = (float*)(smem + L_FBZ);
            for (int r = 0; r < RQB; ++r) {
                if (CNT[r] <= CAP) continue;
                const float* qr = Q + (size_t)(b * TT + t0 + r) * DD;
                const float* Kb = Kf + (size_t)b * TT * DD;
                for (int cc2 = lane; cc2 < TT; cc2 += 64) {
                    const float* kr = Kb + (size_t)cc2 * DD;
                    float a = 0.0f;
                    for (int d = 0; d < DD; ++d) a = fmaf(qr[d], kr[d], a);
                    fbz[cc2] = 0.5f * a;
                }
                __threadfence_block();
                float m = -3.402823466e38f;
                for (int cc2 = lane; cc2 < TT; cc2 += 64) m = fmaxf(m, fbz[cc2]);
                #pragma unroll
                for (int off = 32; off; off >>= 1) m = fmaxf(m, __shfl_xor(m, off));
                float lo = m - 1.0f, hi = m, tau;
                for (int it = 0; it < NITER; ++it) {
                    tau = 0.5f * (lo + hi);
                    float s = 0.0f;
                    for (int cc2 = lane; cc2 < TT; cc2 += 64) {
                        const float tt2 = fmaxf(fbz[cc2] - tau, 0.0f);
                        s = fmaf(tt2, tt2, s);
                    }
                    #pragma unroll
                    for (int off = 32; off; off >>= 1) s += __shfl_xor(s, off);
                    const bool gt = s > 1.0f;
                    lo = gt ? tau : lo;
                    hi = gt ? hi : tau;
                }
                tau = 0.5f * (lo + hi);
                float ssum = 0.0f;
                for (int cc2 = lane; cc2 < TT; cc2 += 64) {
                    const float tt2 = fmaxf(fbz[cc2] - tau, 0.0f);
                    ssum = fmaf(tt2, tt2, ssum);
                }
                #pragma unroll
                for (int off = 32; off; off >>= 1) ssum += __shfl_xor(ssum, off);
                const float inv = 1.0f / ssum;
                const int d4 = lane * 4;
                float4 o = make_float4(0.f, 0.f, 0.f, 0.f);
                for (int s = 0; s < TT; ++s) {
                    const float tt2 = fmaxf(fbz[s] - tau, 0.0f);
                    const float w = tt2 * tt2 * inv;
                    if (w > 0.0f) {
                        const float4 v = *(const float4*)(V + ((size_t)b * TT + s) * DD + d4);
                        o.x = fmaf(w, v.x, o.x); o.y = fmaf(w, v.y, o.y);
                        o.z = fmaf(w, v.z, o.z); o.w = fmaf(w, v.w, o.w);
                    }
                }
                *(float4*)(Out + ((size_t)(b * TT + t0 + r)) * DD + d4) = o;
                if (lane == 0) CNT[r] = -1;
                __threadfence_block();
            }
        }
        __syncthreads();
    }

    // ---------------- scalar per-lane tau + weights ----------------
    {
        const int myrow = wrow0 + (lane & 15);
        const int nRaw = CNT[myrow];
        const int n = (nRaw < 0 || nRaw > CAP) ? 0 : nRaw;
        float cvr[CAP];
        #pragma unroll
        for (int i = 0; i < CAP; ++i)
            cvr[i] = (i < n) ? CVAL[myrow * CAP + i] : -3.0e30f;
        float emax = cvr[0];
        #pragma unroll
        for (int i = 1; i < CAP; ++i) emax = fmaxf(emax, cvr[i]);
        float lo = emax - 1.0f, hi = emax;
        for (int it = 0; it < NITER; ++it) {
            const float tau = 0.5f * (lo + hi);
            float s = 0.0f;
            #pragma unroll
            for (int i = 0; i < CAP; ++i) {
                const float tt2 = fmaxf(cvr[i] - tau, 0.0f);
                s = fmaf(tt2, tt2, s);
            }
            const bool gt = s > 1.0f;
            lo = gt ? tau : lo;
            hi = gt ? hi : tau;
        }
        const float tau = 0.5f * (lo + hi);
        float ssum = 0.0f;
        #pragma unroll
        for (int i = 0; i < CAP; ++i) {
            const float tt2 = fmaxf(cvr[i] - tau, 0.0f);
            ssum = fmaf(tt2, tt2, ssum);
        }
        const float inv = 1.0f / ssum;
        if (lane < 16 && n > 0) {
            for (int i = 0; i < n; ++i) {
                const float tt2 = fmaxf(cvr[i] - tau, 0.0f);
                CVAL[myrow * CAP + i] = tt2 * tt2 * inv;
            }
        }
    }

    // ---------------- sparse PV via broadcast LDS reads ----------------
    const float* Vb = V + (size_t)b * TT * DD;
    for (int j = 0; j < 16; ++j) {
        const int row = wrow0 + j;
        const int n = CNT[row];
        if (n < 0 || n > CAP) continue;      // slow path handled
        const int d4 = lane * 4;
        float4 o = make_float4(0.f, 0.f, 0.f, 0.f);
        for (int i = 0; i < n; ++i) {
            const float wi = CVAL[row * CAP + i];
            if (wi > 0.0f) {
                const int si = (int)CIDX[row * CAP + i];
                const float4 v = *(const float4*)(Vb + (size_t)si * DD + d4);
                o.x = fmaf(wi, v.x, o.x); o.y = fmaf(wi, v.y, o.y);
                o.z = fmaf(wi, v.z, o.z); o.w = fmaf(wi, v.w, o.w);
            }
        }
        *(float4*)(Out + ((size_t)(b * TT + t0 + row)) * DD + d4) = o;
    }
}

// ---------------- round-1 kernel kept as ws-size fallback ----------------
#define DOT4(A, Kv, Qv) \
    A = fmaf((Qv).x, (Kv).x, fmaf((Qv).y, (Kv).y, fmaf((Qv).z, (Kv).z, fmaf((Qv).w, (Kv).w, (A)))))

__launch_bounds__(256, 2)
__global__ void entmax_fallback_kernel(const float* __restrict__ Q,
                                       const float* __restrict__ V,
                                       const float* __restrict__ K,
                                       float* __restrict__ Out) {
    extern __shared__ float zshf[];
    const int tid = threadIdx.x;
    const int b   = blockIdx.x >> 8;
    const int t0  = (blockIdx.x & 255) * 8;
    const float* Qb = Q + ((size_t)b * TT + t0) * DD;
    const float* Kb = K + (size_t)b * TT * DD;
    const float* Vb = V + (size_t)b * TT * DD;
    for (int g = 0; g < 2; ++g) {
        const int c0 = (g << 10) + tid;
        const float* k0 = Kb + (size_t)c0 * DD;
        float4 acc[8];
        #pragma unroll
        for (int r = 0; r < 8; ++r) acc[r] = make_float4(0.f, 0.f, 0.f, 0.f);
        for (int d = 0; d < DD; d += 4) {
            const float4 ka = *(const float4*)(k0 + d);
            const float4 kb = *(const float4*)(k0 + 256 * DD + d);
            const float4 kc = *(const float4*)(k0 + 512 * DD + d);
            const float4 kd = *(const float4*)(k0 + 768 * DD + d);
            #pragma unroll
            for (int r = 0; r < 8; ++r) {
                const float4 qv = *(const float4*)(Qb + r * DD + d);
                DOT4(acc[r].x, ka, qv); DOT4(acc[r].y, kb, qv);
                DOT4(acc[r].z, kc, qv); DOT4(acc[r].w, kd, qv);
            }
        }
        #pragma unroll
        for (int r = 0; r < 8; ++r) {
            zshf[r * TT + c0      ] = 0.5f * acc[r].x;
            zshf[r * TT + c0 + 256] = 0.5f * acc[r].y;
            zshf[r * TT + c0 + 512] = 0.5f * acc[r].z;
            zshf[r * TT + c0 + 768] = 0.5f * acc[r].w;
        }
    }
    __syncthreads();
    {
        const int wid = tid >> 6, lane = tid & 63;
        for (int rr = 0; rr < 2; ++rr) {
            const int r = wid * 2 + rr;
            float* z = zshf + r * TT;
            float zv[32];
            float m = -3.402823466e38f;
            #pragma unroll
            for (int j = 0; j < 32; ++j) { zv[j] = z[lane + (j << 6)]; m = fmaxf(m, zv[j]); }
            #pragma unroll
            for (int off = 32; off; off >>= 1) m = fmaxf(m, __shfl_xor(m, off));
            float lo = m - 1.0f, hi = m;
            for (int it = 0; it < NITER; ++it) {
                const float tau = 0.5f * (lo + hi);
                float s = 0.f;
                #pragma unroll
                for (int j = 0; j < 32; ++j) { float t = fmaxf(zv[j] - tau, 0.f); s = fmaf(t, t, s); }
                #pragma unroll
                for (int off = 32; off; off >>= 1) s += __shfl_xor(s, off);
                const bool gt = (s - 1.0f) > 0.0f;
                lo = gt ? tau : lo; hi = gt ? hi : tau;
            }
            const float tau = 0.5f * (lo + hi);
            float ssum = 0.f;
            #pragma unroll
            for (int j = 0; j < 32; ++j) { float t = fmaxf(zv[j] - tau, 0.f); ssum = fmaf(t, t, ssum); }
            #pragma unroll
            for (int off = 32; off; off >>= 1) ssum += __shfl_xor(ssum, off);
            const float inv = 1.0f / ssum;
            #pragma unroll
            for (int j = 0; j < 32; ++j) {
                float t = fmaxf(zv[j] - tau, 0.f);
                z[lane + (j << 6)] = t * t * inv;
            }
        }
    }
    __syncthreads();
    {
        const int d2 = (tid & 127) * 2;
        const int sg = tid >> 7;
        float2 acc[8];
        #pragma unroll
        for (int r = 0; r < 8; ++r) acc[r] = make_float2(0.f, 0.f);
        for (int sc = 0; sc < TT; sc += 8) {
            const int s0 = sc + sg * 4;
            float4 w4[8];
            #pragma unroll
            for (int r = 0; r < 8; ++r) w4[r] = *(const float4*)&zshf[r * TT + s0];
            #pragma unroll
            for (int js = 0; js < 4; ++js) {
                const float2 v = *(const float2*)(Vb + (size_t)(s0 + js) * DD + d2);
                #pragma unroll
                for (int r = 0; r < 8; ++r) {
                    const float wv = (js == 0) ? w4[r].x : (js == 1) ? w4[r].y
                                   : (js == 2) ? w4[r].z : w4[r].w;
                    acc[r].x = fmaf(wv, v.x, acc[r].x);
                    acc[r].y = fmaf(wv, v.y, acc[r].y);
                }
            }
        }
        __syncthreads();
        float* part = zshf;
        if (sg == 1) {
            #pragma unroll
            for (int r = 0; r < 8; ++r) *(float2*)&part[r * DD + d2] = acc[r];
        }
        __syncthreads();
        if (sg == 0) {
            #pragma unroll
            for (int r = 0; r < 8; ++r) {
                const float2 p = *(const float2*)&part[r * DD + d2];
                float2 o; o.x = acc[r].x + p.x; o.y = acc[r].y + p.y;
                *(float2*)&Out[((size_t)b * TT + t0 + r) * DD + d2] = o;
            }
        }
    }
}

extern "C" void kernel_launch(void* const* d_in, const int* in_sizes, int n_in,
                              void* d_out, int out_size, void* d_ws, size_t ws_size,
                              hipStream_t stream) {
    const float* Q = (const float*)d_in[0];   // query
    const float* V = (const float*)d_in[1];   // value (dict order!)
    const float* K = (const float*)d_in[2];   // key
    float* Out = (float*)d_out;
    const int B = in_sizes[0] / (TT * DD);
    const size_t NE = (size_t)B * TT * DD;
    const size_t need = NE * 2;               // Khf bf16

    if (ws_size < need) {                     // defensive fallback (round-1 kernel)
        entmax_fallback_kernel<<<dim3(B * (TT / 8)), 256, 8 * TT * sizeof(float), stream>>>(
            Q, V, K, Out);
        return;
    }

    unsigned short* Khf = (unsigned short*)d_ws;
    pack_k_kernel<<<dim3(B * 256), 256, 0, stream>>>(K, Khf);

    const int nwg = B * (TT / RQB);           // 256 -> 1 block/CU, 8 waves
    (void)hipFuncSetAttribute((const void*)entmax_frag_kernel,
                              hipFuncAttributeMaxDynamicSharedMemorySize, LDS_SZ);
    entmax_frag_kernel<<<dim3(nwg), NT, LDS_SZ, stream>>>(Q, Khf, K, V, Out, nwg);
}